// Round 1
// baseline (573.124 us; speedup 1.0000x reference)
//
#include <hip/hip_runtime.h>
#include <math.h>

// ---------------------------------------------------------------------------
// OptimizedEdgeEnhancement on MI355X — Round 6
//
// R5 post-mortem: rocprof top-5 is all 160us harness fills -> every kernel
// <160us; dur_us flat across R2->R4 restructures of k1's load path -> k1 is
// HBM-fetch-bound, not issue-bound. Root cause: in k1/k4 all 4 waves of a
// block read the SAME pixels (px independent of wave id) -> up to 4x
// redundant x/edge fetch (k1: ~1.07GB vs 268MB ideal).
// Fix: lane owns 2 DISTINCT px and computes ALL 64 outputs (acc[2][64],
// ~155 VGPR, 3 waves/SIMD). Each element read exactly once. Weights are
// block-uniform -> s_load -> v_fma v,s,v. Ring prefetch depth 4 channels
// (1024 FMA-cycles > 900cy HBM latency). k0/k2/k3 unchanged.
// ---------------------------------------------------------------------------

#define HW 65536   // 256*256

// workspace byte offsets
#define WS_WT    0ull                          // 64 KiB  : w_in^T [256][64]
#define WS_Y     65536ull                      // 64 MiB  : y  [4][64][65536]
#define WS_EDGE  (65536ull + 67108864ull)      // 64 MiB  : edge_raw
#define WS_SMALL (65536ull + 134217728ull)     // wavemax[4096], wavesum[4096], w_eff

__global__ __launch_bounds__(256) void k0_prep(const float* __restrict__ w_in,
                                               float* __restrict__ wT) {
    const int tid = threadIdx.x;
    for (int i = tid; i < 64 * 256; i += 256) {
        int o = i >> 8, c = i & 255;
        wT[c * 64 + o] = w_in[i];
    }
}

// One channel: 128 FMAs (2 px x 64 outputs). Weights from block-uniform
// address -> s_load_dwordx4; xv = 2 pixels in VGPRs.
#define CH64(xv, wrow)                                                        \
    {                                                                         \
        _Pragma("unroll")                                                     \
        for (int o4 = 0; o4 < 16; ++o4) {                                     \
            float4 w = *(const float4*)((wrow) + 4 * o4);                     \
            acc0[4*o4+0] = fmaf((xv).x, w.x, acc0[4*o4+0]);                   \
            acc0[4*o4+1] = fmaf((xv).x, w.y, acc0[4*o4+1]);                   \
            acc0[4*o4+2] = fmaf((xv).x, w.z, acc0[4*o4+2]);                   \
            acc0[4*o4+3] = fmaf((xv).x, w.w, acc0[4*o4+3]);                   \
            acc1[4*o4+0] = fmaf((xv).y, w.x, acc1[4*o4+0]);                   \
            acc1[4*o4+1] = fmaf((xv).y, w.y, acc1[4*o4+1]);                   \
            acc1[4*o4+2] = fmaf((xv).y, w.z, acc1[4*o4+2]);                   \
            acc1[4*o4+3] = fmaf((xv).y, w.w, acc1[4*o4+3]);                   \
        }                                                                     \
    }

// conv1x1 256->64. Block = 512 distinct px (thread: 2 px), ALL 64 outputs.
// Each x element read exactly once. 512 blocks total.
__global__ __launch_bounds__(256) void k1_convin(const float* __restrict__ x,
                                                 const float* __restrict__ wT,
                                                 const float* __restrict__ b_in,
                                                 float* __restrict__ y) {
    const int tid = threadIdx.x;
    const int blk = blockIdx.x;
    const int b   = blk >> 7;                       // 128 blocks / batch
    const int px  = ((blk & 127) << 9) + (tid << 1);

    const float* xp = x + (size_t)(b << 8) * HW + px;

    float acc0[64], acc1[64];
#pragma unroll
    for (int o = 0; o < 64; ++o) {
        float bv = b_in[o];
        acc0[o] = bv; acc1[o] = bv;
    }

    float2 xr0 = *(const float2*)(xp + 0 * (size_t)HW);
    float2 xr1 = *(const float2*)(xp + 1 * (size_t)HW);
    float2 xr2 = *(const float2*)(xp + 2 * (size_t)HW);
    float2 xr3 = *(const float2*)(xp + 3 * (size_t)HW);

#pragma unroll 1
    for (int cc = 0; cc < 256; cc += 4) {
        const int gn = (cc + 4) & 255;              // tail wraps harmlessly
        float2 n0 = *(const float2*)(xp + (size_t)(gn    ) * HW);
        float2 n1 = *(const float2*)(xp + (size_t)(gn + 1) * HW);
        float2 n2 = *(const float2*)(xp + (size_t)(gn + 2) * HW);
        float2 n3 = *(const float2*)(xp + (size_t)(gn + 3) * HW);
        CH64(xr0, wT + (size_t)(cc    ) * 64);
        CH64(xr1, wT + (size_t)(cc + 1) * 64);
        CH64(xr2, wT + (size_t)(cc + 2) * 64);
        CH64(xr3, wT + (size_t)(cc + 3) * 64);
        xr0 = n0; xr1 = n1; xr2 = n2; xr3 = n3;
    }

    float* yb = y + (size_t)(b << 6) * HW + px;
#pragma unroll
    for (int o = 0; o < 64; ++o)
        *(float2*)(yb + (size_t)o * HW) = float2{acc0[o], acc1[o]};
}

// fused gauss5x5 + scharr/lap. 1 wave = one 16-row band of one plane.
// Register stencil, horizontal halo via shuffles; no LDS, no barriers,
// no global atomics (per-task scratch results).
__global__ __launch_bounds__(256) void k2_edge(const float* __restrict__ y,
                                               float* __restrict__ edge,
                                               float* __restrict__ wavemax,
                                               float* __restrict__ wavesum) {
    const int lane = threadIdx.x & 63;
    const int task = blockIdx.x * 4 + (threadIdx.x >> 6);  // 4096 tasks
    const int plane = task >> 4;
    const int r0 = (task & 15) << 4;
    const float* yp = y + (size_t)plane * HW;
    float* ep = edge + (size_t)plane * HW;
    const int col4 = lane << 2;

    const float g = 0.60653066f, G = 0.88249690f;
    const float S1 = 2.f * g + 2.f * G + 1.f;
    const float inv2 = 1.f / (S1 * S1);

    float4 h0{}, h1{}, h2{}, h3{}, h4{};
    float4 s0{}, s1{}, s2{};
    float lmax = 0.f, lsum = 0.f;

    float4 vcur{};
    if (r0 - 3 >= 0) vcur = *(const float4*)(yp + (r0 - 3) * 256 + col4);

    for (int j = r0 - 3; j <= r0 + 18; ++j) {
        // prefetch row j+1
        float4 vnext{};
        const int jn = j + 1;
        if (jn <= r0 + 18 && jn >= 0 && jn < 256)
            vnext = *(const float4*)(yp + jn * 256 + col4);
        float4 v = vcur;
        // horizontal gaussian (zero pad at columns)
        float lz = __shfl(v.z, lane - 1), lw = __shfl(v.w, lane - 1);
        float rx = __shfl(v.x, lane + 1), ry = __shfl(v.y, lane + 1);
        if (lane == 0)  { lz = 0.f; lw = 0.f; }
        if (lane == 63) { rx = 0.f; ry = 0.f; }
        float4 hv;
        hv.x = fmaf(g, lz,  fmaf(G, lw,  fmaf(G, v.y, fmaf(g, v.z, v.x))));
        hv.y = fmaf(g, lw,  fmaf(G, v.x, fmaf(G, v.z, fmaf(g, v.w, v.y))));
        hv.z = fmaf(g, v.x, fmaf(G, v.y, fmaf(G, v.w, fmaf(g, rx, v.z))));
        hv.w = fmaf(g, v.y, fmaf(G, v.z, fmaf(G, rx,  fmaf(g, ry, v.w))));
        h0 = h1; h1 = h2; h2 = h3; h3 = h4; h4 = hv;

        if (j >= r0 + 1) {
            // vertical gaussian -> smoothed row m = j-2
            float4 sv;
            sv.x = (g * (h0.x + h4.x) + G * (h1.x + h3.x) + h2.x) * inv2;
            sv.y = (g * (h0.y + h4.y) + G * (h1.y + h3.y) + h2.y) * inv2;
            sv.z = (g * (h0.z + h4.z) + G * (h1.z + h3.z) + h2.z) * inv2;
            sv.w = (g * (h0.w + h4.w) + G * (h1.w + h3.w) + h2.w) * inv2;
            s0 = s1; s1 = s2; s2 = sv;

            if (j >= r0 + 3) {
                const int er = j - 3;            // edge row in [r0, r0+15]
                float4 A = s0, B = s1, C = s2;   // rows er-1, er, er+1 of sm
                float Alw = __shfl(A.w, lane - 1), Arx = __shfl(A.x, lane + 1);
                float Blw = __shfl(B.w, lane - 1), Brx = __shfl(B.x, lane + 1);
                float Clw = __shfl(C.w, lane - 1), Crx = __shfl(C.x, lane + 1);
                if (lane == 0)  { Alw = 0.f; Blw = 0.f; Clw = 0.f; }
                if (lane == 63) { Arx = 0.f; Brx = 0.f; Crx = 0.f; }
                if (er == 0)   { A = float4{}; Alw = 0.f; Arx = 0.f; }  // sm zero-pad
                if (er == 255) { C = float4{}; Clw = 0.f; Crx = 0.f; }
                float A6[6] = {Alw, A.x, A.y, A.z, A.w, Arx};
                float B6[6] = {Blw, B.x, B.y, B.z, B.w, Brx};
                float C6[6] = {Clw, C.x, C.y, C.z, C.w, Crx};
                float4 e4;
                float* ev = (float*)&e4;
#pragma unroll
                for (int k = 0; k < 4; ++k) {
                    float g0  = 3.f * (A6[k] - A6[k+2]) + 10.f * (B6[k] - B6[k+2])
                              + 3.f * (C6[k] - C6[k+2]);
                    float g90 = 3.f * (A6[k] - C6[k]) + 10.f * (A6[k+1] - C6[k+1])
                              + 3.f * (A6[k+2] - C6[k+2]);
                    float lap = 4.f * B6[k+1] - B6[k] - B6[k+2] - A6[k+1] - C6[k+1];
                    float e = fmaxf(fabsf(g0), fabsf(g90)) + 0.1f * fabsf(lap);
                    ev[k] = e;
                    lmax = fmaxf(lmax, e);
                    lsum += e;
                }
                *(float4*)(ep + er * 256 + col4) = e4;
            }
        }
        vcur = vnext;
    }

    for (int off = 32; off > 0; off >>= 1) {
        lmax = fmaxf(lmax, __shfl_down(lmax, off));
        lsum += __shfl_down(lsum, off);
    }
    if (lane == 0) {
        wavemax[task] = lmax;
        wavesum[task] = lsum;
    }
}

__global__ __launch_bounds__(256) void k3_se(const float* __restrict__ wavemax,
                                             const float* __restrict__ wavesum,
                                             const float* __restrict__ w_fc1,
                                             const float* __restrict__ b_fc1,
                                             const float* __restrict__ w_fc2,
                                             const float* __restrict__ b_fc2,
                                             const float* __restrict__ w_out,
                                             float* __restrict__ w_eff) {
    const int tid = threadIdx.x;
    const int b = tid >> 6, o = tid & 63;
    __shared__ float smax[256];
    __shared__ float ssum[256];   // per-plane sums (plane = tid)
    __shared__ float coef[256];   // scale[b][c] * inv

    // reduce global max over 4096 wave maxima
    float m = 0.f;
    for (int i = tid; i < 4096; i += 256) m = fmaxf(m, wavemax[i]);
    smax[tid] = m;
    // per-plane sum of 16 band sums (deterministic order)
    float ps = 0.f;
#pragma unroll
    for (int k = 0; k < 16; ++k) ps += wavesum[tid * 16 + k];
    ssum[tid] = ps;
    __syncthreads();
    for (int s = 128; s > 0; s >>= 1) {
        if (tid < s) smax[tid] = fmaxf(smax[tid], smax[tid + s]);
        __syncthreads();
    }
    const float mx = smax[0];
    const float inv = 1.f / (mx + 1e-8f);

    float h[4];
#pragma unroll
    for (int j = 0; j < 4; ++j) h[j] = b_fc1[j];
    for (int c = 0; c < 64; ++c) {
        float pooled = ssum[b * 64 + c] * inv * (1.f / 65536.f);
#pragma unroll
        for (int j = 0; j < 4; ++j) h[j] = fmaf(pooled, w_fc1[j * 64 + c], h[j]);
    }
#pragma unroll
    for (int j = 0; j < 4; ++j) h[j] = fmaxf(h[j], 0.f);
    float z = b_fc2[o];
#pragma unroll
    for (int j = 0; j < 4; ++j) z = fmaf(h[j], w_fc2[o * 4 + j], z);
    float sc = 1.f / (1.f + expf(-z));
    coef[tid] = sc * inv;
    __syncthreads();
    // w_eff[b][c][o] = w_out[o][c] * coef[b][c]
    for (int c = 0; c < 64; ++c)
        w_eff[((b * 64) + c) * 64 + o] = w_out[o * 64 + c] * coef[b * 64 + c];
}

// conv1x1 64->64 with per-batch folded weights. Same single-read layout:
// thread = 2 distinct px, all 64 outputs. 512 blocks.
__global__ __launch_bounds__(256) void k4_out(const float* __restrict__ edge,
                                              const float* __restrict__ w_eff,
                                              const float* __restrict__ b_out,
                                              float* __restrict__ out) {
    const int tid = threadIdx.x;
    const int blk = blockIdx.x;
    const int b   = blk >> 7;
    const int px  = ((blk & 127) << 9) + (tid << 1);

    const float* eb = edge + (size_t)(b << 6) * HW + px;
    const float* wb = w_eff + (b << 12);            // block-uniform base

    float acc0[64], acc1[64];
#pragma unroll
    for (int o = 0; o < 64; ++o) {
        float bv = b_out[o];
        acc0[o] = bv; acc1[o] = bv;
    }

    float2 xr0 = *(const float2*)(eb + 0 * (size_t)HW);
    float2 xr1 = *(const float2*)(eb + 1 * (size_t)HW);
    float2 xr2 = *(const float2*)(eb + 2 * (size_t)HW);
    float2 xr3 = *(const float2*)(eb + 3 * (size_t)HW);

#pragma unroll 1
    for (int cc = 0; cc < 64; cc += 4) {
        const int gn = (cc + 4) & 63;               // tail wraps harmlessly
        float2 n0 = *(const float2*)(eb + (size_t)(gn    ) * HW);
        float2 n1 = *(const float2*)(eb + (size_t)(gn + 1) * HW);
        float2 n2 = *(const float2*)(eb + (size_t)(gn + 2) * HW);
        float2 n3 = *(const float2*)(eb + (size_t)(gn + 3) * HW);
        CH64(xr0, wb + (size_t)(cc    ) * 64);
        CH64(xr1, wb + (size_t)(cc + 1) * 64);
        CH64(xr2, wb + (size_t)(cc + 2) * 64);
        CH64(xr3, wb + (size_t)(cc + 3) * 64);
        xr0 = n0; xr1 = n1; xr2 = n2; xr3 = n3;
    }

    float* ob = out + (size_t)(b << 6) * HW + px;
#pragma unroll
    for (int o = 0; o < 64; ++o)
        *(float2*)(ob + (size_t)o * HW) = float2{acc0[o], acc1[o]};
}

extern "C" void kernel_launch(void* const* d_in, const int* in_sizes, int n_in,
                              void* d_out, int out_size, void* d_ws, size_t ws_size,
                              hipStream_t stream) {
    const float* x     = (const float*)d_in[0];
    const float* w_in  = (const float*)d_in[1];
    const float* b_in  = (const float*)d_in[2];
    const float* w_fc1 = (const float*)d_in[3];
    const float* b_fc1 = (const float*)d_in[4];
    const float* w_fc2 = (const float*)d_in[5];
    const float* b_fc2 = (const float*)d_in[6];
    const float* w_out = (const float*)d_in[7];
    const float* b_out = (const float*)d_in[8];

    char* ws = (char*)d_ws;
    float* wT      = (float*)(ws + WS_WT);
    float* y       = (float*)(ws + WS_Y);
    float* edge    = (float*)(ws + WS_EDGE);
    float* wavemax = (float*)(ws + WS_SMALL);            // 4096 floats
    float* wavesum = (float*)(ws + WS_SMALL + 16384);    // 4096 floats
    float* w_eff   = (float*)(ws + WS_SMALL + 32768);    // 4*64*64 floats
    float* out     = (float*)d_out;

    hipLaunchKernelGGL(k0_prep,  dim3(1),   dim3(256), 0, stream, w_in, wT);
    hipLaunchKernelGGL(k1_convin,dim3(512), dim3(256), 0, stream, x, wT, b_in, y);
    hipLaunchKernelGGL(k2_edge,  dim3(1024),dim3(256), 0, stream, y, edge, wavemax, wavesum);
    hipLaunchKernelGGL(k3_se,    dim3(1),   dim3(256), 0, stream, wavemax, wavesum,
                       w_fc1, b_fc1, w_fc2, b_fc2, w_out, w_eff);
    hipLaunchKernelGGL(k4_out,   dim3(512), dim3(256), 0, stream, edge, w_eff, b_out, out);
}

// Round 3
// 502.598 us; speedup vs baseline: 1.1403x; 1.1403x over previous
//
#include <hip/hip_runtime.h>
#include <math.h>

// ---------------------------------------------------------------------------
// OptimizedEdgeEnhancement on MI355X — Round 8 (= R7 resubmit; infra flake)
//
// R6 post-mortem: k1=192us, 13% HBM, 31% VALU, Occ 23% (232 regs -> 2
// waves/SIMD). Traffic near-ideal (FETCH 135MB) -> latency-bound.
// Root cause: vmcnt completes IN-ORDER; weight loads (L1-fast) queue
// behind HBM x-prefetches (~900cy), so every channel's FMA burst waits
// on HBM latency. Explains R3-neutral and R5's 44% VALU too.
// Fix: weights -> LDS (lgkmcnt path, wave-uniform ds_read broadcast);
// vmcnt carries ONLY the x stream (8-deep reload-after-use ring, ~1090cy
// distance). k1: 2x 128-ch weight tiles (32KB LDS). k4: 16KB once.
// Mapping: lane=4px, wave=16 outs (acc 64 regs + ~85 addr/ring ->
// 3 waves/SIMD target). k0/k2/k3 unchanged.
// ---------------------------------------------------------------------------

#define HW 65536   // 256*256

// workspace byte offsets
#define WS_WT    0ull                          // 64 KiB  : w_in^T [256][64]
#define WS_Y     65536ull                      // 64 MiB  : y  [4][64][65536]
#define WS_EDGE  (65536ull + 67108864ull)      // 64 MiB  : edge_raw
#define WS_SMALL (65536ull + 134217728ull)     // wavemax[4096], wavesum[4096], w_eff

__global__ __launch_bounds__(256) void k0_prep(const float* __restrict__ w_in,
                                               float* __restrict__ wT) {
    const int tid = threadIdx.x;
    for (int i = tid; i < 64 * 256; i += 256) {
        int o = i >> 8, c = i & 255;
        wT[c * 64 + o] = w_in[i];
    }
}

// conv1x1 256->64. Block: 256 px tile; wave wv computes outputs
// [16wv,16wv+16) for all 256 px; lane = 4 px. Weights staged in LDS
// (128-ch tiles), read as wave-uniform ds_read_b128 (broadcast).
// x: 8-deep register ring, reload-after-use -> vmcnt queue is pure x.
__global__ __launch_bounds__(256) void k1_convin(const float* __restrict__ x,
                                                 const float* __restrict__ wT,
                                                 const float* __restrict__ b_in,
                                                 float* __restrict__ y) {
    __shared__ float s_w[128 * 64];            // 32 KiB: [ch within tile][out]
    const int tid  = threadIdx.x;
    const int lane = tid & 63;
    const int og   = __builtin_amdgcn_readfirstlane((tid >> 6) << 4); // 0,16,32,48
    const int blk  = blockIdx.x;
    const int b    = blk >> 8;
    const int px   = ((blk & 255) << 8) + (lane << 2);

    const float* xp = x + (size_t)(b << 8) * HW + px;

    float acc[4][16];
#pragma unroll
    for (int oi = 0; oi < 16; ++oi) {
        float bv = b_in[og + oi];
        acc[0][oi] = bv; acc[1][oi] = bv; acc[2][oi] = bv; acc[3][oi] = bv;
    }

    // x ring: 8 channels deep
    float4 xr[8];
#pragma unroll
    for (int i = 0; i < 8; ++i) xr[i] = *(const float4*)(xp + (size_t)i * HW);

#pragma unroll
    for (int t = 0; t < 2; ++t) {              // two 128-channel weight tiles
        __syncthreads();                       // tile t-1 consumers done
        // stage 128*64 floats: 256 thr x 32 floats (8x float4 each)
#pragma unroll
        for (int r = 0; r < 8; ++r) {
            const int idx = r * 1024 + tid * 4;
            *(float4*)&s_w[idx] = *(const float4*)&wT[t * 8192 + idx];
        }
        __syncthreads();

        const int cbase = t << 7;
#pragma unroll 1
        for (int c8 = 0; c8 < 128; c8 += 8) {
#pragma unroll
            for (int i = 0; i < 8; ++i) {
                const int c = cbase + c8 + i;          // global channel
                float4 xv = xr[i];
                // reload slot for channel c+8 (wraps harmlessly at the end)
                xr[i] = *(const float4*)(xp + (size_t)((c + 8) & 255) * HW);
                const float* wrow = &s_w[((c8 + i) << 6) + og];
                float4 w0 = *(const float4*)(wrow);
                float4 w1 = *(const float4*)(wrow + 4);
                float4 w2 = *(const float4*)(wrow + 8);
                float4 w3 = *(const float4*)(wrow + 12);
                float wf[16] = {w0.x,w0.y,w0.z,w0.w, w1.x,w1.y,w1.z,w1.w,
                                w2.x,w2.y,w2.z,w2.w, w3.x,w3.y,w3.z,w3.w};
#pragma unroll
                for (int oi = 0; oi < 16; ++oi) {
                    acc[0][oi] = fmaf(xv.x, wf[oi], acc[0][oi]);
                    acc[1][oi] = fmaf(xv.y, wf[oi], acc[1][oi]);
                    acc[2][oi] = fmaf(xv.z, wf[oi], acc[2][oi]);
                    acc[3][oi] = fmaf(xv.w, wf[oi], acc[3][oi]);
                }
            }
        }
    }

    float* yb = y + (size_t)(b << 6) * HW + px;
#pragma unroll
    for (int oi = 0; oi < 16; ++oi)
        *(float4*)(yb + (size_t)(og + oi) * HW) = float4{acc[0][oi], acc[1][oi],
                                                         acc[2][oi], acc[3][oi]};
}

// fused gauss5x5 + scharr/lap. 1 wave = one 16-row band of one plane.
// Register stencil, horizontal halo via shuffles; no LDS, no barriers,
// no global atomics (per-task scratch results).
__global__ __launch_bounds__(256) void k2_edge(const float* __restrict__ y,
                                               float* __restrict__ edge,
                                               float* __restrict__ wavemax,
                                               float* __restrict__ wavesum) {
    const int lane = threadIdx.x & 63;
    const int task = blockIdx.x * 4 + (threadIdx.x >> 6);  // 4096 tasks
    const int plane = task >> 4;
    const int r0 = (task & 15) << 4;
    const float* yp = y + (size_t)plane * HW;
    float* ep = edge + (size_t)plane * HW;
    const int col4 = lane << 2;

    const float g = 0.60653066f, G = 0.88249690f;
    const float S1 = 2.f * g + 2.f * G + 1.f;
    const float inv2 = 1.f / (S1 * S1);

    float4 h0{}, h1{}, h2{}, h3{}, h4{};
    float4 s0{}, s1{}, s2{};
    float lmax = 0.f, lsum = 0.f;

    float4 vcur{};
    if (r0 - 3 >= 0) vcur = *(const float4*)(yp + (r0 - 3) * 256 + col4);

    for (int j = r0 - 3; j <= r0 + 18; ++j) {
        // prefetch row j+1
        float4 vnext{};
        const int jn = j + 1;
        if (jn <= r0 + 18 && jn >= 0 && jn < 256)
            vnext = *(const float4*)(yp + jn * 256 + col4);
        float4 v = vcur;
        // horizontal gaussian (zero pad at columns)
        float lz = __shfl(v.z, lane - 1), lw = __shfl(v.w, lane - 1);
        float rx = __shfl(v.x, lane + 1), ry = __shfl(v.y, lane + 1);
        if (lane == 0)  { lz = 0.f; lw = 0.f; }
        if (lane == 63) { rx = 0.f; ry = 0.f; }
        float4 hv;
        hv.x = fmaf(g, lz,  fmaf(G, lw,  fmaf(G, v.y, fmaf(g, v.z, v.x))));
        hv.y = fmaf(g, lw,  fmaf(G, v.x, fmaf(G, v.z, fmaf(g, v.w, v.y))));
        hv.z = fmaf(g, v.x, fmaf(G, v.y, fmaf(G, v.w, fmaf(g, rx, v.z))));
        hv.w = fmaf(g, v.y, fmaf(G, v.z, fmaf(G, rx,  fmaf(g, ry, v.w))));
        h0 = h1; h1 = h2; h2 = h3; h3 = h4; h4 = hv;

        if (j >= r0 + 1) {
            // vertical gaussian -> smoothed row m = j-2
            float4 sv;
            sv.x = (g * (h0.x + h4.x) + G * (h1.x + h3.x) + h2.x) * inv2;
            sv.y = (g * (h0.y + h4.y) + G * (h1.y + h3.y) + h2.y) * inv2;
            sv.z = (g * (h0.z + h4.z) + G * (h1.z + h3.z) + h2.z) * inv2;
            sv.w = (g * (h0.w + h4.w) + G * (h1.w + h3.w) + h2.w) * inv2;
            s0 = s1; s1 = s2; s2 = sv;

            if (j >= r0 + 3) {
                const int er = j - 3;            // edge row in [r0, r0+15]
                float4 A = s0, B = s1, C = s2;   // rows er-1, er, er+1 of sm
                float Alw = __shfl(A.w, lane - 1), Arx = __shfl(A.x, lane + 1);
                float Blw = __shfl(B.w, lane - 1), Brx = __shfl(B.x, lane + 1);
                float Clw = __shfl(C.w, lane - 1), Crx = __shfl(C.x, lane + 1);
                if (lane == 0)  { Alw = 0.f; Blw = 0.f; Clw = 0.f; }
                if (lane == 63) { Arx = 0.f; Brx = 0.f; Crx = 0.f; }
                if (er == 0)   { A = float4{}; Alw = 0.f; Arx = 0.f; }  // sm zero-pad
                if (er == 255) { C = float4{}; Clw = 0.f; Crx = 0.f; }
                float A6[6] = {Alw, A.x, A.y, A.z, A.w, Arx};
                float B6[6] = {Blw, B.x, B.y, B.z, B.w, Brx};
                float C6[6] = {Clw, C.x, C.y, C.z, C.w, Crx};
                float4 e4;
                float* ev = (float*)&e4;
#pragma unroll
                for (int k = 0; k < 4; ++k) {
                    float g0  = 3.f * (A6[k] - A6[k+2]) + 10.f * (B6[k] - B6[k+2])
                              + 3.f * (C6[k] - C6[k+2]);
                    float g90 = 3.f * (A6[k] - C6[k]) + 10.f * (A6[k+1] - C6[k+1])
                              + 3.f * (A6[k+2] - C6[k+2]);
                    float lap = 4.f * B6[k+1] - B6[k] - B6[k+2] - A6[k+1] - C6[k+1];
                    float e = fmaxf(fabsf(g0), fabsf(g90)) + 0.1f * fabsf(lap);
                    ev[k] = e;
                    lmax = fmaxf(lmax, e);
                    lsum += e;
                }
                *(float4*)(ep + er * 256 + col4) = e4;
            }
        }
        vcur = vnext;
    }

    for (int off = 32; off > 0; off >>= 1) {
        lmax = fmaxf(lmax, __shfl_down(lmax, off));
        lsum += __shfl_down(lsum, off);
    }
    if (lane == 0) {
        wavemax[task] = lmax;
        wavesum[task] = lsum;
    }
}

__global__ __launch_bounds__(256) void k3_se(const float* __restrict__ wavemax,
                                             const float* __restrict__ wavesum,
                                             const float* __restrict__ w_fc1,
                                             const float* __restrict__ b_fc1,
                                             const float* __restrict__ w_fc2,
                                             const float* __restrict__ b_fc2,
                                             const float* __restrict__ w_out,
                                             float* __restrict__ w_eff) {
    const int tid = threadIdx.x;
    const int b = tid >> 6, o = tid & 63;
    __shared__ float smax[256];
    __shared__ float ssum[256];   // per-plane sums (plane = tid)
    __shared__ float coef[256];   // scale[b][c] * inv

    // reduce global max over 4096 wave maxima
    float m = 0.f;
    for (int i = tid; i < 4096; i += 256) m = fmaxf(m, wavemax[i]);
    smax[tid] = m;
    // per-plane sum of 16 band sums (deterministic order)
    float ps = 0.f;
#pragma unroll
    for (int k = 0; k < 16; ++k) ps += wavesum[tid * 16 + k];
    ssum[tid] = ps;
    __syncthreads();
    for (int s = 128; s > 0; s >>= 1) {
        if (tid < s) smax[tid] = fmaxf(smax[tid], smax[tid + s]);
        __syncthreads();
    }
    const float mx = smax[0];
    const float inv = 1.f / (mx + 1e-8f);

    float h[4];
#pragma unroll
    for (int j = 0; j < 4; ++j) h[j] = b_fc1[j];
    for (int c = 0; c < 64; ++c) {
        float pooled = ssum[b * 64 + c] * inv * (1.f / 65536.f);
#pragma unroll
        for (int j = 0; j < 4; ++j) h[j] = fmaf(pooled, w_fc1[j * 64 + c], h[j]);
    }
#pragma unroll
    for (int j = 0; j < 4; ++j) h[j] = fmaxf(h[j], 0.f);
    float z = b_fc2[o];
#pragma unroll
    for (int j = 0; j < 4; ++j) z = fmaf(h[j], w_fc2[o * 4 + j], z);
    float sc = 1.f / (1.f + expf(-z));
    coef[tid] = sc * inv;
    __syncthreads();
    // w_eff[b][c][o] = w_out[o][c] * coef[b][c]
    for (int c = 0; c < 64; ++c)
        w_eff[((b * 64) + c) * 64 + o] = w_out[o * 64 + c] * coef[b * 64 + c];
}

// conv1x1 64->64, per-batch folded weights staged once in LDS (16 KiB).
// Same mapping as k1: lane = 4 px, wave = 16 outputs; 8-deep edge ring.
__global__ __launch_bounds__(256) void k4_out(const float* __restrict__ edge,
                                              const float* __restrict__ w_eff,
                                              const float* __restrict__ b_out,
                                              float* __restrict__ out) {
    __shared__ float s_w[64 * 64];             // 16 KiB: [ch][out]
    const int tid  = threadIdx.x;
    const int lane = tid & 63;
    const int og   = __builtin_amdgcn_readfirstlane((tid >> 6) << 4);
    const int blk  = blockIdx.x;
    const int b    = blk >> 8;
    const int px   = ((blk & 255) << 8) + (lane << 2);

    const float* eb = edge + (size_t)(b << 6) * HW + px;
    const float* wb = w_eff + (b << 12);

    // stage weights: 4096 floats = 256 thr x 16 floats
#pragma unroll
    for (int r = 0; r < 4; ++r) {
        const int idx = r * 1024 + tid * 4;
        *(float4*)&s_w[idx] = *(const float4*)&wb[idx];
    }

    float acc[4][16];
#pragma unroll
    for (int oi = 0; oi < 16; ++oi) {
        float bv = b_out[og + oi];
        acc[0][oi] = bv; acc[1][oi] = bv; acc[2][oi] = bv; acc[3][oi] = bv;
    }

    float4 xr[8];
#pragma unroll
    for (int i = 0; i < 8; ++i) xr[i] = *(const float4*)(eb + (size_t)i * HW);

    __syncthreads();

#pragma unroll 1
    for (int c8 = 0; c8 < 64; c8 += 8) {
#pragma unroll
        for (int i = 0; i < 8; ++i) {
            const int c = c8 + i;
            float4 xv = xr[i];
            xr[i] = *(const float4*)(eb + (size_t)((c + 8) & 63) * HW);
            const float* wrow = &s_w[(c << 6) + og];
            float4 w0 = *(const float4*)(wrow);
            float4 w1 = *(const float4*)(wrow + 4);
            float4 w2 = *(const float4*)(wrow + 8);
            float4 w3 = *(const float4*)(wrow + 12);
            float wf[16] = {w0.x,w0.y,w0.z,w0.w, w1.x,w1.y,w1.z,w1.w,
                            w2.x,w2.y,w2.z,w2.w, w3.x,w3.y,w3.z,w3.w};
#pragma unroll
            for (int oi = 0; oi < 16; ++oi) {
                acc[0][oi] = fmaf(xv.x, wf[oi], acc[0][oi]);
                acc[1][oi] = fmaf(xv.y, wf[oi], acc[1][oi]);
                acc[2][oi] = fmaf(xv.z, wf[oi], acc[2][oi]);
                acc[3][oi] = fmaf(xv.w, wf[oi], acc[3][oi]);
            }
        }
    }

    float* ob = out + (size_t)(b << 6) * HW + px;
#pragma unroll
    for (int oi = 0; oi < 16; ++oi)
        *(float4*)(ob + (size_t)(og + oi) * HW) = float4{acc[0][oi], acc[1][oi],
                                                         acc[2][oi], acc[3][oi]};
}

extern "C" void kernel_launch(void* const* d_in, const int* in_sizes, int n_in,
                              void* d_out, int out_size, void* d_ws, size_t ws_size,
                              hipStream_t stream) {
    const float* x     = (const float*)d_in[0];
    const float* w_in  = (const float*)d_in[1];
    const float* b_in  = (const float*)d_in[2];
    const float* w_fc1 = (const float*)d_in[3];
    const float* b_fc1 = (const float*)d_in[4];
    const float* w_fc2 = (const float*)d_in[5];
    const float* b_fc2 = (const float*)d_in[6];
    const float* w_out = (const float*)d_in[7];
    const float* b_out = (const float*)d_in[8];

    char* ws = (char*)d_ws;
    float* wT      = (float*)(ws + WS_WT);
    float* y       = (float*)(ws + WS_Y);
    float* edge    = (float*)(ws + WS_EDGE);
    float* wavemax = (float*)(ws + WS_SMALL);            // 4096 floats
    float* wavesum = (float*)(ws + WS_SMALL + 16384);    // 4096 floats
    float* w_eff   = (float*)(ws + WS_SMALL + 32768);    // 4*64*64 floats
    float* out     = (float*)d_out;

    hipLaunchKernelGGL(k0_prep,  dim3(1),    dim3(256), 0, stream, w_in, wT);
    hipLaunchKernelGGL(k1_convin,dim3(1024), dim3(256), 0, stream, x, wT, b_in, y);
    hipLaunchKernelGGL(k2_edge,  dim3(1024), dim3(256), 0, stream, y, edge, wavemax, wavesum);
    hipLaunchKernelGGL(k3_se,    dim3(1),    dim3(256), 0, stream, wavemax, wavesum,
                       w_fc1, b_fc1, w_fc2, b_fc2, w_out, w_eff);
    hipLaunchKernelGGL(k4_out,   dim3(1024), dim3(256), 0, stream, edge, w_eff, b_out, out);
}